// Round 15
// baseline (294.683 us; speedup 1.0000x reference)
//
#include <hip/hip_runtime.h>
#include <hip/hip_bf16.h>
#include <stdint.h>

typedef __bf16 bf16;
typedef __bf16 bf16x8 __attribute__((ext_vector_type(8)));
typedef __bf16 bf16x4 __attribute__((ext_vector_type(4)));
typedef float f32x4 __attribute__((ext_vector_type(4)));
typedef float f32x16 __attribute__((ext_vector_type(16)));

#define B_ 2
#define L_ 2048
#define E_ 2048
#define H_ 16
#define HKV_ 2
#define G_ 8
#define D_ 128
#define SPAST_ 2048
#define S_ 4096
#define EKV_ 256
#define QKVN 2560   // fused projection width: E + 2*EKV
#define KOFF 2048   // k columns start
#define VOFF 2304   // v columns start

#define MFMA16(a, b, c) __builtin_amdgcn_mfma_f32_16x16x32_bf16(a, b, c, 0, 0, 0)
#define MFMA32(a, b, c) __builtin_amdgcn_mfma_f32_32x32x16_bf16(a, b, c, 0, 0, 0)

__device__ __forceinline__ void gload16(const bf16* g, bf16* l) {
  __builtin_amdgcn_global_load_lds(
      (__attribute__((address_space(1))) void*)g,
      (__attribute__((address_space(3))) void*)l, 16, 0, 0);
}

// ---------------- fused f32 -> bf16 conversion: 5 buffers, one launch ----------------
__global__ void cvt5_kernel(const float* __restrict__ sx, const float* __restrict__ swq,
                            const float* __restrict__ swk, const float* __restrict__ swv,
                            const float* __restrict__ swo, bf16* __restrict__ dx,
                            bf16* __restrict__ dwqkv, bf16* __restrict__ dwo) {
  int blk = blockIdx.x;
  const float* s;
  bf16* d;
  int base;
  if (blk < 8192) { s = sx; d = dx; base = blk; }
  else if (blk < 12288) { s = swq; d = dwqkv; base = blk - 8192; }
  else if (blk < 12800) { s = swk; d = dwqkv + (size_t)E_ * E_; base = blk - 12288; }
  else if (blk < 13312) { s = swv; d = dwqkv + (size_t)(E_ + EKV_) * E_; base = blk - 12800; }
  else { s = swo; d = dwo; base = blk - 13312; }
  size_t i = ((size_t)base * 256 + threadIdx.x) * 4;
  float4 v = *(const float4*)(s + i);
  bf16x4 o;
  o[0] = (bf16)v.x; o[1] = (bf16)v.y; o[2] = (bf16)v.z; o[3] = (bf16)v.w;
  *(bf16x4*)(d + i) = o;
}

// ---------------- trig table ----------------
__global__ void trig_kernel(const int* __restrict__ offp, float2* __restrict__ trig) {
  int l = blockIdx.x, j = threadIdx.x;  // 64 threads
  float inv = exp2f(-(float)j * (13.287712379549449f / 64.0f));  // log2(10000)
  float ang = (float)(*offp + l) * inv;
  trig[l * 64 + j] = make_float2(cosf(ang), sinf(ang));
}

// ---------------- concat biases ----------------
__global__ void biascat_kernel(const float* __restrict__ bq, const float* __restrict__ bk,
                               const float* __restrict__ bv, float* __restrict__ cb) {
  int i = blockIdx.x * 256 + threadIdx.x;  // grid 10 x 256 = 2560
  float v;
  if (i < E_) v = bq[i];
  else if (i < E_ + EKV_) v = bk[i - E_];
  else v = bv[i - E_ - EKV_];
  cb[i] = v;
}

// ---------------- NT GEMM (R9-proven): 2-phase dbuf, __syncthreads ----------------
template <int OUTF32>
__global__ __launch_bounds__(256) void gemm_nt(const bf16* __restrict__ A,
                                               const bf16* __restrict__ Bw,
                                               const float* __restrict__ bias,
                                               void* __restrict__ Cout,
                                               int M, int N, int K) {
  __shared__ bf16 As[2 * 128 * 64];
  __shared__ bf16 Bs[2 * 128 * 64];
  const int tid = threadIdx.x;
  const int wid = tid >> 6, lane = tid & 63;
  const int ln15 = lane & 15, lq = lane >> 4;
  const int row0 = blockIdx.x * 128, col0 = blockIdx.y * 128;
  const int wr = wid >> 1, wc = wid & 1;
  f32x4 acc[4][4] = {};
  char* AsB = (char*)As;
  char* BsB = (char*)Bs;

  auto STAGE = [&](int buf, int k0) {
    char* ad = AsB + buf * 16384;
    char* bd = BsB + buf * 16384;
#pragma unroll
    for (int j = 0; j < 4; j++) {
      int cid = j * 256 + tid;
      int r = cid >> 3, c = cid & 7;
      int csw = (c ^ (r & 7)) << 3;
      gload16(A + (size_t)(row0 + r) * K + k0 + csw, (bf16*)(ad + (j * 256 + wid * 64) * 16));
      gload16(Bw + (size_t)(col0 + r) * K + k0 + csw, (bf16*)(bd + (j * 256 + wid * 64) * 16));
    }
  };

  STAGE(0, 0);
  __syncthreads();
  int cur = 0;
  for (int k0 = 0; k0 < K; k0 += 64) {
    if (k0 + 64 < K) STAGE(cur ^ 1, k0 + 64);
    char* ac = AsB + cur * 16384;
    char* bc = BsB + cur * 16384;
    bf16x8 af[4][2], bfm[4][2];
#pragma unroll
    for (int m = 0; m < 4; m++) {
#pragma unroll
      for (int kk = 0; kk < 2; kk++) {
        int Ra = wr * 64 + m * 16 + ln15;
        int Rb = wc * 64 + m * 16 + ln15;
        int c = (kk << 2) + lq;
        af[m][kk] = *(const bf16x8*)(ac + Ra * 128 + ((c ^ (Ra & 7)) << 4));
        bfm[m][kk] = *(const bf16x8*)(bc + Rb * 128 + ((c ^ (Rb & 7)) << 4));
      }
    }
    __builtin_amdgcn_s_setprio(1);
#pragma unroll
    for (int m = 0; m < 4; m++)
#pragma unroll
      for (int n = 0; n < 4; n++)
#pragma unroll
        for (int kk = 0; kk < 2; kk++)
          acc[m][n] = MFMA16(af[m][kk], bfm[n][kk], acc[m][n]);
    __builtin_amdgcn_s_setprio(0);
    __syncthreads();
    cur ^= 1;
  }
#pragma unroll
  for (int m = 0; m < 4; m++) {
    int gr0 = row0 + wr * 64 + m * 16 + 4 * lq;
#pragma unroll
    for (int n = 0; n < 4; n++) {
      int gc = col0 + wc * 64 + n * 16 + ln15;
      float bv = bias ? bias[gc] : 0.0f;
#pragma unroll
      for (int reg = 0; reg < 4; reg++) {
        float v = acc[m][n][reg] + bv;
        size_t idx = (size_t)(gr0 + reg) * N + gc;
        if (OUTF32)
          ((float*)Cout)[idx] = v;
        else
          ((bf16*)Cout)[idx] = (bf16)v;
      }
    }
  }
}

// ---------------- RoPE on Q (vectorized bf16x8), reads fused qkv_lin ----------------
__global__ void rope_q_kernel(const bf16* __restrict__ qkv_lin, const float2* __restrict__ trig,
                              bf16* __restrict__ qbuf) {
  int bl = blockIdx.x * 2 + (threadIdx.x >> 7);  // grid = B*L/2
  int b = bl >> 11, l = bl & 2047;
  int u = threadIdx.x & 127;
  int h = u >> 3, j0 = (u & 7) * 8;
  const float QS = 0.08838834764831845f * 1.4426950408889634f;  // 1/sqrt(128) * log2(e)
  const bf16* src = qkv_lin + (size_t)bl * QKVN + h * D_ + j0;
  bf16x8 x1 = *(const bf16x8*)(src);
  bf16x8 x2 = *(const bf16x8*)(src + 64);
  bf16x8 o1, o2;
#pragma unroll
  for (int e = 0; e < 8; e++) {
    float2 cs = trig[l * 64 + j0 + e];
    float a = (float)x1[e], c = (float)x2[e];
    o1[e] = (bf16)((a * cs.x - c * cs.y) * QS);
    o2[e] = (bf16)((c * cs.x + a * cs.y) * QS);
  }
  size_t o = ((size_t)(b * H_ + h) * L_ + l) * D_ + j0;
  *(bf16x8*)(qbuf + o) = o1;
  *(bf16x8*)(qbuf + o + 64) = o2;
}

// ---------------- build k_all (B,HKV,S,D), reads fused qkv_lin ----------------
__global__ void build_k_kernel(const float* __restrict__ k_cache, const bf16* __restrict__ qkv_lin,
                               const float2* __restrict__ trig, bf16* __restrict__ k_all) {
  int d = threadIdx.x;  // 128
  int s = blockIdx.x;
  int bz = blockIdx.y;  // b*HKV + hkv
  size_t oidx = ((size_t)bz * S_ + s) * D_ + d;
  if (s < SPAST_) {
    k_all[oidx] = (bf16)k_cache[((size_t)bz * SPAST_ + s) * D_ + d];
  } else {
    int l = s - SPAST_;
    int b = bz >> 1, kh = bz & 1;
    int j = d & 63;
    float2 cs = trig[l * 64 + j];
    size_t base = (size_t)(b * L_ + l) * QKVN + KOFF + kh * D_;
    float x1 = (float)qkv_lin[base + j];
    float x2 = (float)qkv_lin[base + 64 + j];
    float v = (d < 64) ? (x1 * cs.x - x2 * cs.y) : (x2 * cs.x + x1 * cs.y);
    k_all[oidx] = (bf16)v;
  }
}

// ---------------- build transposed V: vtall (B,HKV,D,S), reads fused qkv_lin ----------------
__global__ void build_vt_kernel(const float* __restrict__ v_cache, const bf16* __restrict__ qkv_lin,
                                bf16* __restrict__ vtall) {
  __shared__ float tile[64][68];
  int s0 = blockIdx.x * 64;
  int d0 = blockIdx.y * 64;
  int bz = blockIdx.z;
  int b = bz >> 1, kh = bz & 1;
#pragma unroll
  for (int it = 0; it < 4; it++) {
    int idx = it * 256 + threadIdx.x;  // 0..1023
    int ss = idx >> 4, dd0 = (idx & 15) * 4;
    int s = s0 + ss;
    float4 v;
    if (s < SPAST_) {
      v = *(const float4*)(v_cache + ((size_t)bz * SPAST_ + s) * D_ + d0 + dd0);
    } else {
      bf16x4 t = *(const bf16x4*)(qkv_lin + (size_t)(b * L_ + (s - SPAST_)) * QKVN + VOFF +
                                  kh * D_ + d0 + dd0);
      v = make_float4((float)t[0], (float)t[1], (float)t[2], (float)t[3]);
    }
    tile[ss][dd0] = v.x; tile[ss][dd0 + 1] = v.y;
    tile[ss][dd0 + 2] = v.z; tile[ss][dd0 + 3] = v.w;
  }
  __syncthreads();
#pragma unroll
  for (int it = 0; it < 4; it++) {
    int idx = it * 256 + threadIdx.x;
    int dd = idx >> 4, ss0 = (idx & 15) * 4;
    bf16x4 o;
#pragma unroll
    for (int e = 0; e < 4; e++) o[e] = (bf16)tile[ss0 + e][dd];
    *(bf16x4*)(vtall + ((size_t)bz * D_ + d0 + dd) * S_ + s0 + ss0) = o;
  }
}

// ---------------- flash attention: 8-wave 256-q blocks, interleaved granules ----------------
// grid (8, 32) x 512 threads. Block x, wave w owns q-rows [x*32 + w*256, +32): every block's
// chunk count is ~uniform (62..64) -> balanced without remap, and blocks per KV slice halve
// (KV L2/L3 traffic -37%, testing the cache-BW-bound theory). Per-wave inner code = R13's
// proven kernel; SK/SV are 2 loads/thread (1024 slots over 512 threads).
__global__ __launch_bounds__(512, 2) void attn_kernel(const bf16* __restrict__ qbuf,
                                                      const bf16* __restrict__ k_all,
                                                      const bf16* __restrict__ vtall,
                                                      bf16* __restrict__ attnout) {
  __shared__ bf16 Ks[2 * 64 * 128];   // [key][d], 256B rows, swizzled 16B slots
  __shared__ bf16 Vs[2 * 64 * 128];   // paired rows: row r = {d=2r | d=2r+1}, 256B
  const int tid = threadIdx.x;
  const int wid = tid >> 6, lane = tid & 63;
  const int l31 = lane & 31, h = lane >> 5;
  const int xq = blockIdx.x;               // 0..7
  const int bh = blockIdx.y;
  const int b = bh / H_, hh = bh % H_;
  const int hkv = hh / G_;
  const bf16* kb = k_all + (size_t)(b * HKV_ + hkv) * S_ * D_;
  const bf16* vb = vtall + (size_t)(b * HKV_ + hkv) * D_ * S_;
  const int qw = xq * 32 + wid * 256;      // wave's 32-row granule (interleaved)
  bf16x8 qf[8];
  {
    const bf16* qp = qbuf + ((size_t)(b * H_ + hh) * L_ + qw + l31) * D_ + h * 8;
#pragma unroll
    for (int ks = 0; ks < 8; ks++) qf[ks] = *(const bf16x8*)(qp + ks * 16);
  }
  f32x16 acc[4] = {};
  float mr = -3e38f, lr = 0.f;

  auto SK = [&](int buf, int s0) {  // 2 loads/thread: K chunk 64x128
    char* kd = (char*)Ks + buf * 16384;
#pragma unroll
    for (int j = 0; j < 2; j++) {
      int cid = j * 512 + tid;
      int r = cid >> 4;
      int cl = (cid & 15) ^ (r & 15);
      gload16(kb + (size_t)(s0 + r) * D_ + cl * 8, (bf16*)(kd + (j * 512 + wid * 64) * 16));
    }
  };
  auto SV = [&](int buf, int s0) {  // 2 loads/thread: V^T chunk, paired d-rows
    char* vd = (char*)Vs + buf * 16384;
#pragma unroll
    for (int j = 0; j < 2; j++) {
      int cid = j * 512 + tid;
      int r = cid >> 4;
      int cl = (cid & 15) ^ (r & 15);
      gload16(vb + (size_t)(2 * r + (cl >> 3)) * S_ + s0 + (cl & 7) * 8,
              (bf16*)(vd + (j * 512 + wid * 64) * 16));
    }
  };

  auto QKT = [&](int buf, f32x16& o0, f32x16& o1) {
    char* kcur = (char*)Ks + buf * 16384;
    __builtin_amdgcn_s_setprio(1);
    {
      f32x16 a = {};
      int R = l31;
#pragma unroll
      for (int ks = 0; ks < 8; ks++) {
        int cl = 2 * ks + h;
        bf16x8 kf = *(const bf16x8*)(kcur + R * 256 + ((cl ^ (R & 15)) << 4));
        a = MFMA32(kf, qf[ks], a);
      }
      o0 = a;
    }
    {
      f32x16 a = {};
      int R = 32 + l31;
#pragma unroll
      for (int ks = 0; ks < 8; ks++) {
        int cl = 2 * ks + h;
        bf16x8 kf = *(const bf16x8*)(kcur + R * 256 + ((cl ^ (R & 15)) << 4));
        a = MFMA32(kf, qf[ks], a);
      }
      o1 = a;
    }
    __builtin_amdgcn_s_setprio(0);
  };

  auto FIN = [&](f32x16& st0, f32x16& st1, int s0, int vbuf) {
    char* vcur = (char*)Vs + vbuf * 16384;
    if (s0 + 63 > qw + SPAST_) {
      int q = qw + l31;
#pragma unroll
      for (int r = 0; r < 16; r++) {
        int key0 = s0 + (r & 3) + 8 * (r >> 2) + 4 * h;
        if (key0 > q + SPAST_) st0[r] = -1e30f;
        if (key0 + 32 > q + SPAST_) st1[r] = -1e30f;
      }
    }
    float t0 = fmaxf(fmaxf(st0[0], st0[1]), fmaxf(st0[2], st0[3]));
    float t1 = fmaxf(fmaxf(st0[4], st0[5]), fmaxf(st0[6], st0[7]));
    float t2 = fmaxf(fmaxf(st0[8], st0[9]), fmaxf(st0[10], st0[11]));
    float t3 = fmaxf(fmaxf(st0[12], st0[13]), fmaxf(st0[14], st0[15]));
    float u0 = fmaxf(fmaxf(st1[0], st1[1]), fmaxf(st1[2], st1[3]));
    float u1 = fmaxf(fmaxf(st1[4], st1[5]), fmaxf(st1[6], st1[7]));
    float u2 = fmaxf(fmaxf(st1[8], st1[9]), fmaxf(st1[10], st1[11]));
    float u3 = fmaxf(fmaxf(st1[12], st1[13]), fmaxf(st1[14], st1[15]));
    float mt = fmaxf(fmaxf(fmaxf(t0, t1), fmaxf(t2, t3)),
                     fmaxf(fmaxf(u0, u1), fmaxf(u2, u3)));
    mt = fmaxf(mt, __shfl_xor(mt, 32));
    if (__any(mt - mr > 8.0f)) {  // T13 defer-max
      float mn = fmaxf(mr, mt);
      float fac = exp2f(mr - mn);
      mr = mn;
      lr *= fac;
#pragma unroll
      for (int dt = 0; dt < 4; dt++) acc[dt] *= fac;
    }
    float sacc[4] = {0.f, 0.f, 0.f, 0.f};
#pragma unroll
    for (int r = 0; r < 16; r++) {
      float p = exp2f(st0[r] - mr);
      st0[r] = p;
      sacc[r & 3] += p;
    }
#pragma unroll
    for (int r = 0; r < 16; r++) {
      float p = exp2f(st1[r] - mr);
      st1[r] = p;
      sacc[r & 3] += p;
    }
    float s = (sacc[0] + sacc[1]) + (sacc[2] + sacc[3]);
    s += __shfl_xor(s, 32);
    lr += s;
    uint32_t W[2][8];
#pragma unroll
    for (int j = 0; j < 8; j++)
      asm("v_cvt_pk_bf16_f32 %0, %1, %2" : "=v"(W[0][j]) : "v"(st0[2 * j]), "v"(st0[2 * j + 1]));
#pragma unroll
    for (int j = 0; j < 8; j++)
      asm("v_cvt_pk_bf16_f32 %0, %1, %2" : "=v"(W[1][j]) : "v"(st1[2 * j]), "v"(st1[2 * j + 1]));
#pragma unroll
    for (int t = 0; t < 2; t++)
#pragma unroll
      for (int s4 = 0; s4 < 8; s4 += 4) {
        asm volatile("v_permlane32_swap_b32 %0, %1" : "+v"(W[t][s4 + 0]), "+v"(W[t][s4 + 2]));
        asm volatile("v_permlane32_swap_b32 %0, %1" : "+v"(W[t][s4 + 1]), "+v"(W[t][s4 + 3]));
      }
    __builtin_amdgcn_s_setprio(1);
#pragma unroll
    for (int dt = 0; dt < 4; dt++) {
      int r = dt * 16 + (l31 >> 1);
      int clb = 8 * (l31 & 1) + h;
      f32x16 a = acc[dt];
#pragma unroll
      for (int ks = 0; ks < 4; ks++) {
        int cl = clb + 2 * ks;
        bf16x8 vf = *(const bf16x8*)(vcur + r * 256 + ((cl ^ (r & 15)) << 4));
        union { uint32_t u[4]; bf16x8 v; } pb;
        pb.u[0] = W[ks >> 1][(ks & 1) * 4 + 0];
        pb.u[1] = W[ks >> 1][(ks & 1) * 4 + 1];
        pb.u[2] = W[ks >> 1][(ks & 1) * 4 + 2];
        pb.u[3] = W[ks >> 1][(ks & 1) * 4 + 3];
        a = MFMA32(vf, pb.v, a);
      }
      acc[dt] = a;
    }
    __builtin_amdgcn_s_setprio(0);
  };

  // block-uniform chunk count: max wave is wid=7 -> qmax = xq*32 + 1792 + 31
  int nchunk = (xq * 32 + 7 * 256 + 32 + SPAST_ + 63) >> 6;
  nchunk = (nchunk + 1) & ~1;  // even for unroll-2; <= 64 so staging stays in bounds
  const int smax_w = qw + 32 + SPAST_;

  SK(0, 0);
  SV(0, 0);
  SK(1, 64);
  asm volatile("s_waitcnt vmcnt(2)" ::: "memory");  // K(0),V(0) complete; K(1) in flight
  __builtin_amdgcn_s_barrier();
  f32x16 sA0, sA1, sB0, sB1;
  QKT(0, sA0, sA1);

  for (int i = 0; i < nchunk; i += 2) {
    asm volatile("s_waitcnt vmcnt(0)" ::: "memory");
    __builtin_amdgcn_s_barrier();
    if (i + 1 < nchunk && (i + 1) * 64 < smax_w) QKT((i + 1) & 1, sB0, sB1);
    if (i + 2 < nchunk) SK(i & 1, (i + 2) * 64);
    if (i + 1 < nchunk) SV((i + 1) & 1, (i + 1) * 64);
    if (i * 64 < smax_w) FIN(sA0, sA1, i * 64, i & 1);
    asm volatile("s_waitcnt vmcnt(0)" ::: "memory");
    __builtin_amdgcn_s_barrier();
    if (i + 2 < nchunk && (i + 2) * 64 < smax_w) QKT(i & 1, sA0, sA1);
    if (i + 3 < nchunk) SK((i + 1) & 1, (i + 3) * 64);
    if (i + 2 < nchunk) SV(i & 1, (i + 2) * 64);
    if ((i + 1) * 64 < smax_w) FIN(sB0, sB1, (i + 1) * 64, (i + 1) & 1);
  }
  {
    float inv = 1.0f / lr;
    int q = qw + l31;
    size_t base = ((size_t)(b * L_ + q) * H_ + hh) * D_;
#pragma unroll
    for (int dt = 0; dt < 4; dt++)
#pragma unroll
      for (int u = 0; u < 4; u++) {
        bf16x4 o;
#pragma unroll
        for (int e = 0; e < 4; e++) o[e] = (bf16)(acc[dt][4 * u + e] * inv);
        *(bf16x4*)(attnout + base + dt * 32 + 8 * u + 4 * h) = o;
      }
  }
}

extern "C" void kernel_launch(void* const* d_in, const int* in_sizes, int n_in,
                              void* d_out, int out_size, void* d_ws, size_t ws_size,
                              hipStream_t stream) {
  const float* x = (const float*)d_in[0];
  const float* wq = (const float*)d_in[1];
  const float* wk = (const float*)d_in[2];
  const float* wv = (const float*)d_in[3];
  const float* wo = (const float*)d_in[4];
  const float* bq = (const float*)d_in[5];
  const float* bk = (const float*)d_in[6];
  const float* bv = (const float*)d_in[7];
  const float* k_cache = (const float*)d_in[8];
  const float* v_cache = (const float*)d_in[9];
  const int* offp = (const int*)d_in[10];

  char* w = (char*)d_ws;
  size_t off = 0;
  auto alloc = [&](size_t bytes) -> char* {
    char* p = w + off;
    off += (bytes + 255) & ~(size_t)255;
    return p;
  };
  const size_t nBLE = (size_t)B_ * L_ * E_;
  const size_t nKV = (size_t)B_ * HKV_ * S_ * D_;
  bf16* xb = (bf16*)alloc(nBLE * 2);
  bf16* wqkvb = (bf16*)alloc((size_t)QKVN * E_ * 2);  // [wq; wk; wv] rows, (2560, 2048)
  bf16* wob = (bf16*)alloc((size_t)E_ * E_ * 2);
  bf16* qkv_lin = (bf16*)alloc((size_t)B_ * L_ * QKVN * 2);
  bf16* qbuf = (bf16*)alloc(nBLE * 2);
  bf16* k_all = (bf16*)alloc(nKV * 2);
  bf16* vtall = (bf16*)alloc(nKV * 2);
  bf16* attnout = (bf16*)alloc(nBLE * 2);
  float2* trig = (float2*)alloc((size_t)L_ * 64 * sizeof(float2));
  float* cbias = (float*)alloc(QKVN * sizeof(float));

  cvt5_kernel<<<17408, 256, 0, stream>>>(x, wq, wk, wv, wo, xb, wqkvb, wob);
  trig_kernel<<<L_, 64, 0, stream>>>(offp, trig);
  biascat_kernel<<<QKVN / 256, 256, 0, stream>>>(bq, bk, bv, cbias);

  const int M = B_ * L_;  // 4096
  gemm_nt<0><<<dim3(M / 128, QKVN / 128), 256, 0, stream>>>(xb, wqkvb, cbias, qkv_lin, M, QKVN, E_);
  rope_q_kernel<<<B_ * L_ / 2, 256, 0, stream>>>(qkv_lin, trig, qbuf);
  build_k_kernel<<<dim3(S_, B_ * HKV_), 128, 0, stream>>>(k_cache, qkv_lin, trig, k_all);
  build_vt_kernel<<<dim3(S_ / 64, D_ / 64, B_ * HKV_), 256, 0, stream>>>(v_cache, qkv_lin, vtall);
  attn_kernel<<<dim3(8, 32), 512, 0, stream>>>(qbuf, k_all, vtall, attnout);
  gemm_nt<1><<<dim3(M / 128, E_ / 128), 256, 0, stream>>>(attnout, wob, nullptr, d_out, M, E_, E_);
}

// Round 16
// 291.306 us; speedup vs baseline: 1.0116x; 1.0116x over previous
//
#include <hip/hip_runtime.h>
#include <hip/hip_bf16.h>
#include <stdint.h>

typedef __bf16 bf16;
typedef __bf16 bf16x8 __attribute__((ext_vector_type(8)));
typedef __bf16 bf16x4 __attribute__((ext_vector_type(4)));
typedef float f32x4 __attribute__((ext_vector_type(4)));
typedef float f32x16 __attribute__((ext_vector_type(16)));

#define B_ 2
#define L_ 2048
#define E_ 2048
#define H_ 16
#define HKV_ 2
#define G_ 8
#define D_ 128
#define SPAST_ 2048
#define S_ 4096
#define EKV_ 256
#define QKVN 2560   // fused projection width: E + 2*EKV
#define KOFF 2048   // k columns start
#define VOFF 2304   // v columns start

#define MFMA16(a, b, c) __builtin_amdgcn_mfma_f32_16x16x32_bf16(a, b, c, 0, 0, 0)
#define MFMA32(a, b, c) __builtin_amdgcn_mfma_f32_32x32x16_bf16(a, b, c, 0, 0, 0)

__device__ __forceinline__ void gload16(const bf16* g, bf16* l) {
  __builtin_amdgcn_global_load_lds(
      (__attribute__((address_space(1))) void*)g,
      (__attribute__((address_space(3))) void*)l, 16, 0, 0);
}

// ---------------- fused f32 -> bf16 conversion: 5 buffers, one launch ----------------
// block ranges: x[0,8192) wq[8192,12288) wk[12288,12800) wv[12800,13312) wo[13312,17408)
__global__ void cvt5_kernel(const float* __restrict__ sx, const float* __restrict__ swq,
                            const float* __restrict__ swk, const float* __restrict__ swv,
                            const float* __restrict__ swo, bf16* __restrict__ dx,
                            bf16* __restrict__ dwqkv, bf16* __restrict__ dwo) {
  int blk = blockIdx.x;
  const float* s;
  bf16* d;
  int base;
  if (blk < 8192) { s = sx; d = dx; base = blk; }
  else if (blk < 12288) { s = swq; d = dwqkv; base = blk - 8192; }
  else if (blk < 12800) { s = swk; d = dwqkv + (size_t)E_ * E_; base = blk - 12288; }
  else if (blk < 13312) { s = swv; d = dwqkv + (size_t)(E_ + EKV_) * E_; base = blk - 12800; }
  else { s = swo; d = dwo; base = blk - 13312; }
  size_t i = ((size_t)base * 256 + threadIdx.x) * 4;
  float4 v = *(const float4*)(s + i);
  bf16x4 o;
  o[0] = (bf16)v.x; o[1] = (bf16)v.y; o[2] = (bf16)v.z; o[3] = (bf16)v.w;
  *(bf16x4*)(d + i) = o;
}

// ---------------- trig table ----------------
__global__ void trig_kernel(const int* __restrict__ offp, float2* __restrict__ trig) {
  int l = blockIdx.x, j = threadIdx.x;  // 64 threads
  float inv = exp2f(-(float)j * (13.287712379549449f / 64.0f));  // log2(10000)
  float ang = (float)(*offp + l) * inv;
  trig[l * 64 + j] = make_float2(cosf(ang), sinf(ang));
}

// ---------------- concat biases: cb[0..2048)=bq, [2048..2304)=bk, [2304..2560)=bv ----------------
__global__ void biascat_kernel(const float* __restrict__ bq, const float* __restrict__ bk,
                               const float* __restrict__ bv, float* __restrict__ cb) {
  int i = blockIdx.x * 256 + threadIdx.x;  // grid 10 x 256 = 2560
  float v;
  if (i < E_) v = bq[i];
  else if (i < E_ + EKV_) v = bk[i - E_];
  else v = bv[i - E_ - EKV_];
  cb[i] = v;
}

// ---------------- NT GEMM (R9-proven): 2-phase dbuf, __syncthreads ----------------
template <int OUTF32>
__global__ __launch_bounds__(256) void gemm_nt(const bf16* __restrict__ A,
                                               const bf16* __restrict__ Bw,
                                               const float* __restrict__ bias,
                                               void* __restrict__ Cout,
                                               int M, int N, int K) {
  __shared__ bf16 As[2 * 128 * 64];
  __shared__ bf16 Bs[2 * 128 * 64];
  const int tid = threadIdx.x;
  const int wid = tid >> 6, lane = tid & 63;
  const int ln15 = lane & 15, lq = lane >> 4;
  const int row0 = blockIdx.x * 128, col0 = blockIdx.y * 128;
  const int wr = wid >> 1, wc = wid & 1;
  f32x4 acc[4][4] = {};
  char* AsB = (char*)As;
  char* BsB = (char*)Bs;

  auto STAGE = [&](int buf, int k0) {
    char* ad = AsB + buf * 16384;
    char* bd = BsB + buf * 16384;
#pragma unroll
    for (int j = 0; j < 4; j++) {
      int cid = j * 256 + tid;
      int r = cid >> 3, c = cid & 7;
      int csw = (c ^ (r & 7)) << 3;
      gload16(A + (size_t)(row0 + r) * K + k0 + csw, (bf16*)(ad + (j * 256 + wid * 64) * 16));
      gload16(Bw + (size_t)(col0 + r) * K + k0 + csw, (bf16*)(bd + (j * 256 + wid * 64) * 16));
    }
  };

  STAGE(0, 0);
  __syncthreads();
  int cur = 0;
  for (int k0 = 0; k0 < K; k0 += 64) {
    if (k0 + 64 < K) STAGE(cur ^ 1, k0 + 64);
    char* ac = AsB + cur * 16384;
    char* bc = BsB + cur * 16384;
    bf16x8 af[4][2], bfm[4][2];
#pragma unroll
    for (int m = 0; m < 4; m++) {
#pragma unroll
      for (int kk = 0; kk < 2; kk++) {
        int Ra = wr * 64 + m * 16 + ln15;
        int Rb = wc * 64 + m * 16 + ln15;
        int c = (kk << 2) + lq;
        af[m][kk] = *(const bf16x8*)(ac + Ra * 128 + ((c ^ (Ra & 7)) << 4));
        bfm[m][kk] = *(const bf16x8*)(bc + Rb * 128 + ((c ^ (Rb & 7)) << 4));
      }
    }
    __builtin_amdgcn_s_setprio(1);
#pragma unroll
    for (int m = 0; m < 4; m++)
#pragma unroll
      for (int n = 0; n < 4; n++)
#pragma unroll
        for (int kk = 0; kk < 2; kk++)
          acc[m][n] = MFMA16(af[m][kk], bfm[n][kk], acc[m][n]);
    __builtin_amdgcn_s_setprio(0);
    __syncthreads();
    cur ^= 1;
  }
#pragma unroll
  for (int m = 0; m < 4; m++) {
    int gr0 = row0 + wr * 64 + m * 16 + 4 * lq;
#pragma unroll
    for (int n = 0; n < 4; n++) {
      int gc = col0 + wc * 64 + n * 16 + ln15;
      float bv = bias ? bias[gc] : 0.0f;
#pragma unroll
      for (int reg = 0; reg < 4; reg++) {
        float v = acc[m][n][reg] + bv;
        size_t idx = (size_t)(gr0 + reg) * N + gc;
        if (OUTF32)
          ((float*)Cout)[idx] = v;
        else
          ((bf16*)Cout)[idx] = (bf16)v;
      }
    }
  }
}

// ---------------- RoPE on Q (vectorized bf16x8), reads fused qkv_lin ----------------
__global__ void rope_q_kernel(const bf16* __restrict__ qkv_lin, const float2* __restrict__ trig,
                              bf16* __restrict__ qbuf) {
  int bl = blockIdx.x * 2 + (threadIdx.x >> 7);  // grid = B*L/2
  int b = bl >> 11, l = bl & 2047;
  int u = threadIdx.x & 127;
  int h = u >> 3, j0 = (u & 7) * 8;
  const float QS = 0.08838834764831845f * 1.4426950408889634f;  // 1/sqrt(128) * log2(e)
  const bf16* src = qkv_lin + (size_t)bl * QKVN + h * D_ + j0;
  bf16x8 x1 = *(const bf16x8*)(src);
  bf16x8 x2 = *(const bf16x8*)(src + 64);
  bf16x8 o1, o2;
#pragma unroll
  for (int e = 0; e < 8; e++) {
    float2 cs = trig[l * 64 + j0 + e];
    float a = (float)x1[e], c = (float)x2[e];
    o1[e] = (bf16)((a * cs.x - c * cs.y) * QS);
    o2[e] = (bf16)((c * cs.x + a * cs.y) * QS);
  }
  size_t o = ((size_t)(b * H_ + h) * L_ + l) * D_ + j0;
  *(bf16x8*)(qbuf + o) = o1;
  *(bf16x8*)(qbuf + o + 64) = o2;
}

// ---------------- build k_all (B,HKV,S,D), reads fused qkv_lin ----------------
__global__ void build_k_kernel(const float* __restrict__ k_cache, const bf16* __restrict__ qkv_lin,
                               const float2* __restrict__ trig, bf16* __restrict__ k_all) {
  int d = threadIdx.x;  // 128
  int s = blockIdx.x;
  int bz = blockIdx.y;  // b*HKV + hkv
  size_t oidx = ((size_t)bz * S_ + s) * D_ + d;
  if (s < SPAST_) {
    k_all[oidx] = (bf16)k_cache[((size_t)bz * SPAST_ + s) * D_ + d];
  } else {
    int l = s - SPAST_;
    int b = bz >> 1, kh = bz & 1;
    int j = d & 63;
    float2 cs = trig[l * 64 + j];
    size_t base = (size_t)(b * L_ + l) * QKVN + KOFF + kh * D_;
    float x1 = (float)qkv_lin[base + j];
    float x2 = (float)qkv_lin[base + 64 + j];
    float v = (d < 64) ? (x1 * cs.x - x2 * cs.y) : (x2 * cs.x + x1 * cs.y);
    k_all[oidx] = (bf16)v;
  }
}

// ---------------- build transposed V: vtall (B,HKV,D,S), reads fused qkv_lin ----------------
__global__ void build_vt_kernel(const float* __restrict__ v_cache, const bf16* __restrict__ qkv_lin,
                                bf16* __restrict__ vtall) {
  __shared__ float tile[64][68];
  int s0 = blockIdx.x * 64;
  int d0 = blockIdx.y * 64;
  int bz = blockIdx.z;
  int b = bz >> 1, kh = bz & 1;
#pragma unroll
  for (int it = 0; it < 4; it++) {
    int idx = it * 256 + threadIdx.x;  // 0..1023
    int ss = idx >> 4, dd0 = (idx & 15) * 4;
    int s = s0 + ss;
    float4 v;
    if (s < SPAST_) {
      v = *(const float4*)(v_cache + ((size_t)bz * SPAST_ + s) * D_ + d0 + dd0);
    } else {
      bf16x4 t = *(const bf16x4*)(qkv_lin + (size_t)(b * L_ + (s - SPAST_)) * QKVN + VOFF +
                                  kh * D_ + d0 + dd0);
      v = make_float4((float)t[0], (float)t[1], (float)t[2], (float)t[3]);
    }
    tile[ss][dd0] = v.x; tile[ss][dd0 + 1] = v.y;
    tile[ss][dd0 + 2] = v.z; tile[ss][dd0 + 3] = v.w;
  }
  __syncthreads();
#pragma unroll
  for (int it = 0; it < 4; it++) {
    int idx = it * 256 + threadIdx.x;
    int dd = idx >> 4, ss0 = (idx & 15) * 4;
    bf16x4 o;
#pragma unroll
    for (int e = 0; e < 4; e++) o[e] = (bf16)tile[ss0 + e][dd];
    *(bf16x4*)(vtall + ((size_t)bz * D_ + d0 + dd) * S_ + s0 + ss0) = o;
  }
}

// ---------------- flash attention (R13, best measured: 175.5 us) ----------------
__global__ __launch_bounds__(256, 2) void attn_kernel(const bf16* __restrict__ qbuf,
                                                      const bf16* __restrict__ k_all,
                                                      const bf16* __restrict__ vtall,
                                                      bf16* __restrict__ attnout) {
  __shared__ bf16 Ks[2 * 64 * 128];   // [key][d], 256B rows, swizzled 16B slots
  __shared__ bf16 Vs[2 * 64 * 128];   // paired rows: row r = {d=2r | d=2r+1}, 256B
  const int tid = threadIdx.x;
  const int wid = tid >> 6, lane = tid & 63;
  const int l31 = lane & 31, h = lane >> 5;
  const int xq = ((blockIdx.y >> 4) & 1) ? (15 - (int)blockIdx.x) : (int)blockIdx.x;
  const int q0 = xq * 128;
  const int bh = blockIdx.y;
  const int b = bh / H_, hh = bh % H_;
  const int hkv = hh / G_;
  const bf16* kb = k_all + (size_t)(b * HKV_ + hkv) * S_ * D_;
  const bf16* vb = vtall + (size_t)(b * HKV_ + hkv) * D_ * S_;
  const int qw = q0 + wid * 32;
  bf16x8 qf[8];
  {
    const bf16* qp = qbuf + ((size_t)(b * H_ + hh) * L_ + qw + l31) * D_ + h * 8;
#pragma unroll
    for (int ks = 0; ks < 8; ks++) qf[ks] = *(const bf16x8*)(qp + ks * 16);
  }
  f32x16 acc[4] = {};
  float mr = -3e38f, lr = 0.f;

  auto SK = [&](int buf, int s0) {
    char* kd = (char*)Ks + buf * 16384;
#pragma unroll
    for (int j = 0; j < 4; j++) {
      int cid = j * 256 + tid;
      int r = cid >> 4;
      int cl = (cid & 15) ^ (r & 15);
      gload16(kb + (size_t)(s0 + r) * D_ + cl * 8, (bf16*)(kd + (j * 256 + wid * 64) * 16));
    }
  };
  auto SV = [&](int buf, int s0) {
    char* vd = (char*)Vs + buf * 16384;
#pragma unroll
    for (int j = 0; j < 4; j++) {
      int cid = j * 256 + tid;
      int r = cid >> 4;
      int cl = (cid & 15) ^ (r & 15);
      gload16(vb + (size_t)(2 * r + (cl >> 3)) * S_ + s0 + (cl & 7) * 8,
              (bf16*)(vd + (j * 256 + wid * 64) * 16));
    }
  };

  auto QKT = [&](int buf, f32x16& o0, f32x16& o1) {
    char* kcur = (char*)Ks + buf * 16384;
    __builtin_amdgcn_s_setprio(1);
    {
      f32x16 a = {};
      int R = l31;
#pragma unroll
      for (int ks = 0; ks < 8; ks++) {
        int cl = 2 * ks + h;
        bf16x8 kf = *(const bf16x8*)(kcur + R * 256 + ((cl ^ (R & 15)) << 4));
        a = MFMA32(kf, qf[ks], a);
      }
      o0 = a;
    }
    {
      f32x16 a = {};
      int R = 32 + l31;
#pragma unroll
      for (int ks = 0; ks < 8; ks++) {
        int cl = 2 * ks + h;
        bf16x8 kf = *(const bf16x8*)(kcur + R * 256 + ((cl ^ (R & 15)) << 4));
        a = MFMA32(kf, qf[ks], a);
      }
      o1 = a;
    }
    __builtin_amdgcn_s_setprio(0);
  };

  auto FIN = [&](f32x16& st0, f32x16& st1, int s0, int vbuf) {
    char* vcur = (char*)Vs + vbuf * 16384;
    if (s0 + 63 > qw + SPAST_) {
      int q = qw + l31;
#pragma unroll
      for (int r = 0; r < 16; r++) {
        int key0 = s0 + (r & 3) + 8 * (r >> 2) + 4 * h;
        if (key0 > q + SPAST_) st0[r] = -1e30f;
        if (key0 + 32 > q + SPAST_) st1[r] = -1e30f;
      }
    }
    float t0 = fmaxf(fmaxf(st0[0], st0[1]), fmaxf(st0[2], st0[3]));
    float t1 = fmaxf(fmaxf(st0[4], st0[5]), fmaxf(st0[6], st0[7]));
    float t2 = fmaxf(fmaxf(st0[8], st0[9]), fmaxf(st0[10], st0[11]));
    float t3 = fmaxf(fmaxf(st0[12], st0[13]), fmaxf(st0[14], st0[15]));
    float u0 = fmaxf(fmaxf(st1[0], st1[1]), fmaxf(st1[2], st1[3]));
    float u1 = fmaxf(fmaxf(st1[4], st1[5]), fmaxf(st1[6], st1[7]));
    float u2 = fmaxf(fmaxf(st1[8], st1[9]), fmaxf(st1[10], st1[11]));
    float u3 = fmaxf(fmaxf(st1[12], st1[13]), fmaxf(st1[14], st1[15]));
    float mt = fmaxf(fmaxf(fmaxf(t0, t1), fmaxf(t2, t3)),
                     fmaxf(fmaxf(u0, u1), fmaxf(u2, u3)));
    mt = fmaxf(mt, __shfl_xor(mt, 32));
    if (__any(mt - mr > 8.0f)) {  // T13 defer-max
      float mn = fmaxf(mr, mt);
      float fac = exp2f(mr - mn);
      mr = mn;
      lr *= fac;
#pragma unroll
      for (int dt = 0; dt < 4; dt++) acc[dt] *= fac;
    }
    float sacc[4] = {0.f, 0.f, 0.f, 0.f};
#pragma unroll
    for (int r = 0; r < 16; r++) {
      float p = exp2f(st0[r] - mr);
      st0[r] = p;
      sacc[r & 3] += p;
    }
#pragma unroll
    for (int r = 0; r < 16; r++) {
      float p = exp2f(st1[r] - mr);
      st1[r] = p;
      sacc[r & 3] += p;
    }
    float s = (sacc[0] + sacc[1]) + (sacc[2] + sacc[3]);
    s += __shfl_xor(s, 32);
    lr += s;
    uint32_t W[2][8];
#pragma unroll
    for (int j = 0; j < 8; j++)
      asm("v_cvt_pk_bf16_f32 %0, %1, %2" : "=v"(W[0][j]) : "v"(st0[2 * j]), "v"(st0[2 * j + 1]));
#pragma unroll
    for (int j = 0; j < 8; j++)
      asm("v_cvt_pk_bf16_f32 %0, %1, %2" : "=v"(W[1][j]) : "v"(st1[2 * j]), "v"(st1[2 * j + 1]));
#pragma unroll
    for (int t = 0; t < 2; t++)
#pragma unroll
      for (int s4 = 0; s4 < 8; s4 += 4) {
        asm volatile("v_permlane32_swap_b32 %0, %1" : "+v"(W[t][s4 + 0]), "+v"(W[t][s4 + 2]));
        asm volatile("v_permlane32_swap_b32 %0, %1" : "+v"(W[t][s4 + 1]), "+v"(W[t][s4 + 3]));
      }
    __builtin_amdgcn_s_setprio(1);
#pragma unroll
    for (int dt = 0; dt < 4; dt++) {
      int r = dt * 16 + (l31 >> 1);
      int clb = 8 * (l31 & 1) + h;
      f32x16 a = acc[dt];
#pragma unroll
      for (int ks = 0; ks < 4; ks++) {
        int cl = clb + 2 * ks;
        bf16x8 vf = *(const bf16x8*)(vcur + r * 256 + ((cl ^ (r & 15)) << 4));
        union { uint32_t u[4]; bf16x8 v; } pb;
        pb.u[0] = W[ks >> 1][(ks & 1) * 4 + 0];
        pb.u[1] = W[ks >> 1][(ks & 1) * 4 + 1];
        pb.u[2] = W[ks >> 1][(ks & 1) * 4 + 2];
        pb.u[3] = W[ks >> 1][(ks & 1) * 4 + 3];
        a = MFMA32(vf, pb.v, a);
      }
      acc[dt] = a;
    }
    __builtin_amdgcn_s_setprio(0);
  };

  const int nchunk = (q0 + 128 + SPAST_) >> 6;  // 34 + 2*xq, always even
  const int smax_w = qw + 32 + SPAST_;

  SK(0, 0);
  SV(0, 0);
  SK(1, 64);
  asm volatile("s_waitcnt vmcnt(4)" ::: "memory");
  __builtin_amdgcn_s_barrier();
  f32x16 sA0, sA1, sB0, sB1;
  QKT(0, sA0, sA1);

  for (int i = 0; i < nchunk; i += 2) {
    asm volatile("s_waitcnt vmcnt(0)" ::: "memory");
    __builtin_amdgcn_s_barrier();
    if (i + 1 < nchunk && (i + 1) * 64 < smax_w) QKT((i + 1) & 1, sB0, sB1);
    if (i + 2 < nchunk) SK(i & 1, (i + 2) * 64);
    if (i + 1 < nchunk) SV((i + 1) & 1, (i + 1) * 64);
    if (i * 64 < smax_w) FIN(sA0, sA1, i * 64, i & 1);
    asm volatile("s_waitcnt vmcnt(0)" ::: "memory");
    __builtin_amdgcn_s_barrier();
    if (i + 2 < nchunk && (i + 2) * 64 < smax_w) QKT(i & 1, sA0, sA1);
    if (i + 3 < nchunk) SK((i + 1) & 1, (i + 3) * 64);
    if (i + 2 < nchunk) SV(i & 1, (i + 2) * 64);
    if ((i + 1) * 64 < smax_w) FIN(sB0, sB1, (i + 1) * 64, (i + 1) & 1);
  }
  {
    float inv = 1.0f / lr;
    int q = qw + l31;
    size_t base = ((size_t)(b * L_ + q) * H_ + hh) * D_;
#pragma unroll
    for (int dt = 0; dt < 4; dt++)
#pragma unroll
      for (int u = 0; u < 4; u++) {
        bf16x4 o;
#pragma unroll
        for (int e = 0; e < 4; e++) o[e] = (bf16)(acc[dt][4 * u + e] * inv);
        *(bf16x4*)(attnout + base + dt * 32 + 8 * u + 4 * h) = o;
      }
  }
}

extern "C" void kernel_launch(void* const* d_in, const int* in_sizes, int n_in,
                              void* d_out, int out_size, void* d_ws, size_t ws_size,
                              hipStream_t stream) {
  const float* x = (const float*)d_in[0];
  const float* wq = (const float*)d_in[1];
  const float* wk = (const float*)d_in[2];
  const float* wv = (const float*)d_in[3];
  const float* wo = (const float*)d_in[4];
  const float* bq = (const float*)d_in[5];
  const float* bk = (const float*)d_in[6];
  const float* bv = (const float*)d_in[7];
  const float* k_cache = (const float*)d_in[8];
  const float* v_cache = (const float*)d_in[9];
  const int* offp = (const int*)d_in[10];

  char* w = (char*)d_ws;
  size_t off = 0;
  auto alloc = [&](size_t bytes) -> char* {
    char* p = w + off;
    off += (bytes + 255) & ~(size_t)255;
    return p;
  };
  const size_t nBLE = (size_t)B_ * L_ * E_;
  const size_t nKV = (size_t)B_ * HKV_ * S_ * D_;
  bf16* xb = (bf16*)alloc(nBLE * 2);
  bf16* wqkvb = (bf16*)alloc((size_t)QKVN * E_ * 2);  // [wq; wk; wv] rows, (2560, 2048)
  bf16* wob = (bf16*)alloc((size_t)E_ * E_ * 2);
  bf16* qkv_lin = (bf16*)alloc((size_t)B_ * L_ * QKVN * 2);
  bf16* qbuf = (bf16*)alloc(nBLE * 2);
  bf16* k_all = (bf16*)alloc(nKV * 2);
  bf16* vtall = (bf16*)alloc(nKV * 2);
  bf16* attnout = (bf16*)alloc(nBLE * 2);
  float2* trig = (float2*)alloc((size_t)L_ * 64 * sizeof(float2));
  float* cbias = (float*)alloc(QKVN * sizeof(float));

  cvt5_kernel<<<17408, 256, 0, stream>>>(x, wq, wk, wv, wo, xb, wqkvb, wob);
  trig_kernel<<<L_, 64, 0, stream>>>(offp, trig);
  biascat_kernel<<<QKVN / 256, 256, 0, stream>>>(bq, bk, bv, cbias);

  const int M = B_ * L_;  // 4096
  gemm_nt<0><<<dim3(M / 128, QKVN / 128), 256, 0, stream>>>(xb, wqkvb, cbias, qkv_lin, M, QKVN, E_);
  rope_q_kernel<<<B_ * L_ / 2, 256, 0, stream>>>(qkv_lin, trig, qbuf);
  build_k_kernel<<<dim3(S_, B_ * HKV_), 128, 0, stream>>>(k_cache, qkv_lin, trig, k_all);
  build_vt_kernel<<<dim3(S_ / 64, D_ / 64, B_ * HKV_), 256, 0, stream>>>(v_cache, qkv_lin, vtall);
  attn_kernel<<<dim3(16, 32), 256, 0, stream>>>(qbuf, k_all, vtall, attnout);
  gemm_nt<1><<<dim3(M / 128, E_ / 128), 256, 0, stream>>>(attnout, wob, nullptr, d_out, M, E_, E_);
}